// Round 13
// baseline (1095.534 us; speedup 1.0000x reference)
//
#include <hip/hip_runtime.h>
#include <hip/hip_fp16.h>
#include <math.h>

#define BB 2
#define CDIM 256
#define NHEADS 8
#define HD 32
#define HH 40
#define WW 40
#define NN 1600
#define C3 768
#define SCALE 0.17677669529663687f  // 1/sqrt(32)
#define RTE 8            // rows per block, entropy kernel (2 per wave)
#define RTS 2            // rows per block, sparse kernel (1 wave)
#define TSTR 2048        // tile stride: 32 d * 64 jl
#define HSTR 51200       // per (b,part,h): 25 tiles * 2048

// ---------- helpers ----------
__device__ inline unsigned short fkey16(unsigned short u) {
    return (u & 0x8000) ? (unsigned short)(~u) : (unsigned short)(u | 0x8000);
}
__device__ inline float h16tof(unsigned short b) {
    __half_raw r; r.x = b;
    return __half2float(__half(r));
}
__device__ inline float keytof(unsigned short k) {
    unsigned short v = (k & 0x8000) ? (unsigned short)(k ^ 0x8000) : (unsigned short)(~k);
    return h16tof(v);
}

// reduce-scatter acc[32] over 64 lanes; lane l (and l+32) gets total of element bitrev5(l&31)
__device__ inline float reduce_scatter32(float (&v)[32], int lane) {
#pragma unroll
    for (int step = 0; step < 5; step++) {
        const int off = 1 << step;
        const bool up = (lane >> step) & 1;
        const int h = 32 >> (step + 1);
#pragma unroll
        for (int i = 0; i < h; i++) {
            float send = up ? v[i] : v[h + i];
            float recv = __shfl_xor(send, off);
            float keep = up ? v[h + i] : v[i];
            v[i] = keep + recv;
        }
    }
    return v[0] + __shfl_xor(v[0], 32);
}
__device__ inline int scatter_d(int lane) {
    return ((lane & 1) << 4) | ((lane & 2) << 2) | (lane & 4) | ((lane >> 2) & 2) | ((lane >> 4) & 1);
}

// ---------- 1x1 conv: 8 output channels per thread ----------
__global__ __launch_bounds__(256) void conv1x1_kernel(const float* __restrict__ x,
                                                      const float* __restrict__ w,
                                                      const float* __restrict__ bias,
                                                      float* __restrict__ out) {
    int blk = blockIdx.x;
    int st = blk % 7;
    int t2 = blk / 7;
    int ocg = t2 % (C3 / 8);
    int b = t2 / (C3 / 8);
    int s = st * 256 + threadIdx.x;
    if (s >= NN) return;
    int oc0 = ocg * 8;
    const float* xb = x + (size_t)b * CDIM * NN + s;
    const float* w0 = w + (size_t)oc0 * CDIM;
    float a[8];
#pragma unroll
    for (int i = 0; i < 8; i++) a[i] = bias[oc0 + i];
#pragma unroll 4
    for (int ic = 0; ic < CDIM; ic++) {
        float xv = xb[(size_t)ic * NN];
#pragma unroll
        for (int i = 0; i < 8; i++) a[i] += w0[i * CDIM + ic] * xv;
    }
    float* ob = out + ((size_t)b * C3 + oc0) * NN + s;
#pragma unroll
    for (int i = 0; i < 8; i++) ob[(size_t)i * NN] = a[i];
}

// ---------- depthwise 3x3 pad1; writes j-tiled layout [b][part][h][kt][d][jl] ----------
__global__ __launch_bounds__(256) void dwconv_kernel(const float* __restrict__ in,
                                                     const float* __restrict__ w,
                                                     const float* __restrict__ bias,
                                                     float* __restrict__ out_t) {
    int idx = blockIdx.x * 256 + threadIdx.x;
    int s = idx % NN;
    int t = idx / NN;
    int c = t % C3;
    int b = t / C3;
    int y = s / WW, xx = s % WW;
    const float* ib = in + ((size_t)b * C3 + c) * NN;
    const float* wr = w + (size_t)c * 9;
    float acc = bias[c];
#pragma unroll
    for (int ky = 0; ky < 3; ky++) {
        int iy = y + ky - 1;
        if (iy < 0 || iy >= HH) continue;
#pragma unroll
        for (int kx = 0; kx < 3; kx++) {
            int ix = xx + kx - 1;
            if (ix < 0 || ix >= WW) continue;
            acc += wr[ky * 3 + kx] * ib[iy * WW + ix];
        }
    }
    int part = c >> 8;
    int r = c & 255;
    int hh = r >> 5;
    int d = r & 31;
    out_t[((size_t)(b * 3 + part) * NHEADS + hh) * HSTR + (s >> 6) * TSTR + d * 64 + (s & 63)] = acc;
}

// ---------- phase 1: streaming entropy on tiled layout (r12-proven) ----------
__global__ __launch_bounds__(256) void entropy_kernel(const float* __restrict__ qkv_t,
                                                      float* __restrict__ ent) {
    int blk = blockIdx.x;      // bh*(NN/RTE) + rt
    int rt = blk % (NN / RTE);
    int bh = blk / (NN / RTE);
    int h = bh % NHEADS, b = bh / NHEADS;
    int row0 = rt * RTE;
    __shared__ float Qs[RTE][HD];
    int tid = threadIdx.x;
    const float* qt = qkv_t + ((size_t)(b * 3 + 0) * NHEADS + h) * HSTR;
    const float* ktb = qkv_t + ((size_t)(b * 3 + 1) * NHEADS + h) * HSTR;
    {
        int r = tid >> 5, d = tid & 31;
        int row = row0 + r;
        Qs[r][d] = qt[(row >> 6) * TSTR + d * 64 + (row & 63)];
    }
    __syncthreads();
    int w = tid >> 6, lane = tid & 63;
    int lr0 = 2 * w, lr1 = lr0 + 1;
    float q0[HD], q1[HD];
#pragma unroll
    for (int d = 0; d < HD; d++) { q0[d] = Qs[lr0][d]; q1[d] = Qs[lr1][d]; }
    float S0 = 0.f, T0 = 0.f, S1 = 0.f, T1 = 0.f;
#pragma unroll 1
    for (int kt = 0; kt < 25; kt++) {
        const float* kp = ktb + kt * TSTR + lane;
        float a0 = 0.f, a1 = 0.f;
#pragma unroll
        for (int dc = 0; dc < 4; dc++) {
            float kc[8];
#pragma unroll
            for (int i = 0; i < 8; i++) kc[i] = kp[(dc * 8 + i) * 64];
#pragma unroll
            for (int i = 0; i < 8; i++) {
                a0 += q0[dc * 8 + i] * kc[i];
                a1 += q1[dc * 8 + i] * kc[i];
            }
        }
        a0 *= SCALE; a1 *= SCALE;
        float e0 = __expf(a0), e1 = __expf(a1);
        S0 += e0; T0 += e0 * a0;
        S1 += e1; T1 += e1 * a1;
    }
#pragma unroll
    for (int o = 1; o < 64; o <<= 1) {
        S0 += __shfl_xor(S0, o); T0 += __shfl_xor(T0, o);
        S1 += __shfl_xor(S1, o); T1 += __shfl_xor(T1, o);
    }
    if (lane == 0) {
        ent[(size_t)bh * NN + row0 + lr0] = logf(S0) - T0 / S0;
        ent[(size_t)bh * NN + row0 + lr1] = logf(S1) - T1 / S1;
    }
}

// ---------- gate ----------
__global__ void gate_kernel(const float* __restrict__ ent_rows,
                            const float* __restrict__ g1w, const float* __restrict__ g1b,
                            const float* __restrict__ g2w, const float* __restrict__ g2b,
                            int* __restrict__ keep) {
    int bh = blockIdx.x;
    int tid = threadIdx.x;
    __shared__ float red[4];
    float ls = 0.f;
    for (int j = tid; j < NN; j += 256) ls += ent_rows[bh * NN + j];
    for (int o = 32; o > 0; o >>= 1) ls += __shfl_down(ls, o);
    int lane = tid & 63, wid = tid >> 6;
    if (lane == 0) red[wid] = ls;
    __syncthreads();
    if (tid == 0) {
        float ent = (red[0] + red[1] + red[2] + red[3]) / (float)NN;
        float val = g2b[0];
#pragma unroll
        for (int j = 0; j < 16; j++) {
            float hid = ent * g1w[j] + g1b[j];
            if (hid < 0.f) hid = 0.f;
            val += hid * g2w[j];
        }
        float ratio = 0.9f / (1.f + expf(-val)) + 0.1f;
        int kp = (int)ceilf(ratio * (float)NN);
        if (kp < 1) kp = 1;
        if (kp > NN) kp = NN;
        keep[bh] = kp;
    }
}

// ---------- phase 2: r12 structure + fp16 att keys in LDS + 2-pass radix ----------
__global__ __launch_bounds__(64) void sparse_attn_kernel(const float* __restrict__ qkv_t,
                                                         const int* __restrict__ keep,
                                                         float* __restrict__ oht) {
    int blk = blockIdx.x;
    int rt = blk % (NN / RTS);
    int bh = blk / (NN / RTS);
    int h = bh % NHEADS, b = bh / NHEADS;
    int row0 = rt * RTS;
    __shared__ unsigned att16u[RTS * NN / 2];   // 6.4 KB (key16 pairs)
    __shared__ unsigned hist[RTS][256];         // 2 KB
    __shared__ float Qs[RTS][HD];               // 0.25 KB
    unsigned short* att16 = (unsigned short*)att16u;
    int tid = threadIdx.x;               // 0..63, one wave
    const float* qt = qkv_t + ((size_t)(b * 3 + 0) * NHEADS + h) * HSTR;
    const float* ktb = qkv_t + ((size_t)(b * 3 + 1) * NHEADS + h) * HSTR;
    const float* vtb = qkv_t + ((size_t)(b * 3 + 2) * NHEADS + h) * HSTR;
    {
        int r = tid >> 5, d = tid & 31;
        int row = row0 + r;
        Qs[r][d] = qt[(row >> 6) * TSTR + d * 64 + (row & 63)];
    }
    int want = keep[bh];
    __syncthreads();
    int lane = tid;
    float q0[HD], q1[HD];
#pragma unroll
    for (int d = 0; d < HD; d++) { q0[d] = Qs[0][d]; q1[d] = Qs[1][d]; }

    // ---- QK^T -> fp16 monotone keys in LDS ----
    for (int kt = 0; kt < 25; kt++) {
        const float* kp = ktb + kt * TSTR + lane;
        int j = kt * 64 + lane;
        float kc[HD];
#pragma unroll
        for (int d = 0; d < HD; d++) kc[d] = kp[d * 64];
        float a0 = 0.f, a1 = 0.f;
#pragma unroll
        for (int d = 0; d < HD; d++) { a0 += q0[d] * kc[d]; a1 += q1[d] * kc[d]; }
        a0 *= SCALE; a1 *= SCALE;
        att16[j] = fkey16(__half_as_ushort(__float2half(a0)));
        att16[NN + j] = fkey16(__half_as_ushort(__float2half(a1)));
    }
    __syncthreads();

    // ---- cache packed keys (25 uints = 50 keys) per half-wave row ----
    int l = lane & 31;
    int r = (lane < 32) ? 0 : 1;
    unsigned kvp[25];
#pragma unroll
    for (int i = 0; i < 25; i++) kvp[i] = att16u[r * (NN / 2) + i * 32 + l];

    // ---- 2-pass radix select kth-largest over 16-bit keys ----
    unsigned prefixHigh = 0;
    for (int pass = 0; pass < 2; pass++) {
        int shift = 8 - 8 * pass;
#pragma unroll
        for (int i = 0; i < 8; i++) hist[r][248 - 8 * l + i] = 0u;
#pragma unroll
        for (int i = 0; i < 25; i++) {
            unsigned u = kvp[i];
            unsigned k0 = u & 0xFFFFu, k1 = u >> 16;
            if (pass == 0) {
                atomicAdd(&hist[r][k0 >> 8], 1u);
                atomicAdd(&hist[r][k1 >> 8], 1u);
            } else {
                if ((k0 >> 8) == prefixHigh) atomicAdd(&hist[r][k0 & 255u], 1u);
                if ((k1 >> 8) == prefixHigh) atomicAdd(&hist[r][k1 & 255u], 1u);
            }
        }
        unsigned sch = 0;
#pragma unroll
        for (int i = 0; i < 8; i++) sch += hist[r][248 - 8 * l + i];
        unsigned inc = sch;
#pragma unroll
        for (int dlt = 1; dlt < 32; dlt <<= 1) {
            unsigned tv = __shfl_up(inc, dlt, 32);
            if (l >= dlt) inc += tv;
        }
        unsigned pref = inc - sch;
        bool found = (pref < (unsigned)want) && ((unsigned)want <= inc);
        int bsel = -1, wnew = 0;
        if (found) {
            unsigned want2 = (unsigned)want - pref, cum = 0;
#pragma unroll
            for (int i = 0; i < 8; i++) {
                int bbin = 255 - 8 * l - i;
                unsigned c = hist[r][bbin];
                if (bsel < 0 && cum + c >= want2) { bsel = bbin; wnew = (int)(want2 - cum); }
                cum += c;
            }
        }
        unsigned long long mk = __ballot(found);
        int src = (lane < 32) ? __builtin_ctzll(mk & 0xffffffffULL)
                              : __builtin_ctzll(mk >> 32) + 32;
        bsel = __shfl(bsel, src);
        want = __shfl(wnew, src);
        prefixHigh = (prefixHigh << 8) | (unsigned)bsel;
        (void)shift;
    }
    unsigned kb0 = (unsigned)__shfl((int)prefixHigh, 0);
    unsigned kb1 = (unsigned)__shfl((int)prefixHigh, 32);

    // ---- fused sparse softmax + PV (raw exp; decode keys from LDS) ----
    float acc0[HD], acc1[HD];
#pragma unroll
    for (int d = 0; d < HD; d++) { acc0[d] = 0.f; acc1[d] = 0.f; }
    float S0 = 0.f, S1 = 0.f;
    for (int kt = 0; kt < 25; kt++) {
        const float* vp = vtb + kt * TSTR + lane;
        int j = kt * 64 + lane;
        unsigned k0 = att16[j];
        unsigned k1 = att16[NN + j];
        float p0 = (k0 >= kb0) ? __expf(keytof((unsigned short)k0)) : 0.f;
        float p1 = (k1 >= kb1) ? __expf(keytof((unsigned short)k1)) : 0.f;
        S0 += p0; S1 += p1;
#pragma unroll
        for (int d = 0; d < HD; d++) {
            float vv = vp[d * 64];
            acc0[d] += p0 * vv;
            acc1[d] += p1 * vv;
        }
    }
#pragma unroll
    for (int off = 1; off < 64; off <<= 1) {
        S0 += __shfl_xor(S0, off);
        S1 += __shfl_xor(S1, off);
    }

    // ---- register reduce-scatter across 64 lanes; store ----
    float tot0 = reduce_scatter32(acc0, lane);
    float tot1 = reduce_scatter32(acc1, lane);
    int dd = scatter_d(lane);
    if (lane < 32) {
        size_t base = ((size_t)b * CDIM + h * HD + dd) * NN + row0;
        oht[base + 0] = tot0 / S0;
        oht[base + 1] = tot1 / S1;
    }
}

// ---------- output projection from oht [b][c][n]: 8 oc per thread ----------
__global__ __launch_bounds__(256) void proj_kernel(const float* __restrict__ oht,
                                                   const float* __restrict__ pw,
                                                   const float* __restrict__ pb,
                                                   float* __restrict__ out) {
    int blk = blockIdx.x;
    int st = blk % 7;
    int t2 = blk / 7;
    int ocg = t2 % (CDIM / 8);
    int b = t2 / (CDIM / 8);
    int s = st * 256 + threadIdx.x;
    if (s >= NN) return;
    int co0 = ocg * 8;
    const float* ib = oht + (size_t)b * CDIM * NN + s;
    const float* w0 = pw + (size_t)co0 * CDIM;
    float a[8];
#pragma unroll
    for (int i = 0; i < 8; i++) a[i] = pb[co0 + i];
#pragma unroll 4
    for (int c = 0; c < CDIM; c++) {
        float xv = ib[(size_t)c * NN];
#pragma unroll
        for (int i = 0; i < 8; i++) a[i] += w0[i * CDIM + c] * xv;
    }
    float* ob = out + ((size_t)b * CDIM + co0) * NN + s;
#pragma unroll
    for (int i = 0; i < 8; i++) ob[(size_t)i * NN] = a[i];
}

extern "C" void kernel_launch(void* const* d_in, const int* in_sizes, int n_in,
                              void* d_out, int out_size, void* d_ws, size_t ws_size,
                              hipStream_t stream) {
    const float* x      = (const float*)d_in[0];
    const float* qkv_w  = (const float*)d_in[1];
    const float* qkv_b  = (const float*)d_in[2];
    const float* pos_w  = (const float*)d_in[3];
    const float* pos_b  = (const float*)d_in[4];
    const float* proj_w = (const float*)d_in[5];
    const float* proj_b = (const float*)d_in[6];
    const float* g1w    = (const float*)d_in[7];
    const float* g1b    = (const float*)d_in[8];
    const float* g2w    = (const float*)d_in[9];
    const float* g2b    = (const float*)d_in[10];
    float* out = (float*)d_out;

    float* ws   = (float*)d_ws;
    float* buf1 = ws;                                  // BB*C3*NN  ([b][c][s])
    float* buf2 = buf1 + (size_t)BB * C3 * NN;         // BB*C3*NN  (j-tiled)
    float* ent  = buf2 + (size_t)BB * C3 * NN;         // BB*NHEADS*NN
    float* oht  = ent + (size_t)BB * NHEADS * NN;      // BB*CDIM*NN  ([b][c][n])
    int* keep   = (int*)(oht + (size_t)BB * CDIM * NN);

    conv1x1_kernel<<<BB * (C3 / 8) * 7, 256, 0, stream>>>(x, qkv_w, qkv_b, buf1);
    dwconv_kernel<<<BB * C3 * NN / 256, 256, 0, stream>>>(buf1, pos_w, pos_b, buf2);
    entropy_kernel<<<NHEADS * BB * (NN / RTE), 256, 0, stream>>>(buf2, ent);
    gate_kernel<<<BB * NHEADS, 256, 0, stream>>>(ent, g1w, g1b, g2w, g2b, keep);
    sparse_attn_kernel<<<NHEADS * BB * (NN / RTS), 64, 0, stream>>>(buf2, keep, oht);
    proj_kernel<<<BB * (CDIM / 8) * 7, 256, 0, stream>>>(oht, proj_w, proj_b, out);
}